// Round 1
// baseline (1263.127 us; speedup 1.0000x reference)
//
#include <hip/hip_runtime.h>
#include <hip/hip_bf16.h>

#define MM 32
#define KK 8192
#define NN 28672

typedef _Float16 half8   __attribute__((ext_vector_type(8)));
typedef __fp16   fp16x2  __attribute__((ext_vector_type(2)));
typedef float    floatx4 __attribute__((ext_vector_type(4)));

// ---------------- act fp32 -> fp16 pre-convert (exact: data originated fp16)
__global__ __launch_bounds__(256) void act_cvt_kernel(
    const float* __restrict__ act, __fp16* __restrict__ act16)
{
    int i = (blockIdx.x * 256 + threadIdx.x) * 4;   // MM*KK = 262144 = 256*256*4
    floatx4 v = *(const floatx4*)(act + i);
    fp16x2 lo = __builtin_amdgcn_cvt_pkrtz(v[0], v[1]);
    fp16x2 hi = __builtin_amdgcn_cvt_pkrtz(v[2], v[3]);
    __fp16* o = act16 + i;
    *(fp16x2*)(o)     = lo;
    *(fp16x2*)(o + 2) = hi;
}

// ---------------- streaming GEMM: no LDS, no barriers.
// Each weight element feeds exactly one lane's B-fragment, so every thread
// loads its own 8 fragment ints directly (dword, stride NN). Per load instr a
// wave covers 4 rows x 64B fully-used cache lines. Double-buffered with NAMED
// buffers so all array indexing is compile-time (no scratch), letting the
// compiler emit counted vmcnt waits -> loads from step t+1 stay in flight
// while step t converts+MFMAs. Weight read exactly once: 0.94 GB.
//
// Fragment mapping identical to the previously-verified kernel:
//   b[j] = W[k0 + quad*8 + j][n0],  a = act16[col][k0 + quad*8 + ...],
//   C: m = quad*4 + r (+16), n = n0.
// Block: 256 thr = 4 waves, each wave owns 16 n-cols. Grid: (NN/64, KSPLIT).
template <int KSPLIT>
__global__ __launch_bounds__(256, 6) void gemm_stream_kernel(
    const __fp16*   __restrict__ act16,
    const int*      __restrict__ weight,
    float*          __restrict__ ws)
{
    const int lane = threadIdx.x & 63;
    const int wave = threadIdx.x >> 6;
    const int col  = lane & 15;
    const int quad = lane >> 4;

    const int n0 = blockIdx.x * 64 + wave * 16 + col;
    const int kc = blockIdx.y * (KK / KSPLIT);
    constexpr int NSTEP = (KK / KSPLIT) / 32;   // 64 K-steps of 32

    const int*    wp  = weight + (size_t)(kc + quad * 8) * NN + n0;
    const __fp16* ap0 = act16 + (size_t)col * KK + kc + quad * 8;
    const __fp16* ap1 = ap0 + (size_t)16 * KK;

    floatx4 acc0 = {0.f, 0.f, 0.f, 0.f};   // m = 0..15
    floatx4 acc1 = {0.f, 0.f, 0.f, 0.f};   // m = 16..31

    int   wA[8], wB[8];
    half8 aA0, aA1, aB0, aB1;

    // ---- load one K-step: 8 weight dwords (stride NN) + 2 act half8
    auto load_step = [&](int (&w)[8], half8& a0, half8& a1) {
#pragma unroll
        for (int j = 0; j < 8; ++j)
            w[j] = wp[(size_t)j * NN];
        a0 = *(const half8*)ap0;
        a1 = *(const half8*)ap1;
        wp  += (size_t)32 * NN;
        ap0 += 32;
        ap1 += 32;
    };

    // ---- convert + 2 MFMA for one K-step
    auto compute_step = [&](const int (&w)[8], const half8 a0, const half8 a1) {
        half8 b;
#pragma unroll
        for (int j = 0; j < 4; ++j) {
            fp16x2 p = __builtin_amdgcn_cvt_pkrtz((float)w[2 * j],
                                                  (float)w[2 * j + 1]);
            b[2 * j]     = p[0];
            b[2 * j + 1] = p[1];
        }
        acc0 = __builtin_amdgcn_mfma_f32_16x16x32_f16(a0, b, acc0, 0, 0, 0);
        acc1 = __builtin_amdgcn_mfma_f32_16x16x32_f16(a1, b, acc1, 0, 0, 0);
    };

    load_step(wA, aA0, aA1);                      // step 0 in flight
#pragma unroll 1
    for (int s = 0; s < NSTEP / 2 - 1; ++s) {     // steps 2s, 2s+1
        load_step(wB, aB0, aB1);                  // prefetch odd step
        compute_step(wA, aA0, aA1);
        load_step(wA, aA0, aA1);                  // prefetch next even step
        compute_step(wB, aB0, aB1);
    }
    load_step(wB, aB0, aB1);                      // step NSTEP-1
    compute_step(wA, aA0, aA1);                   // step NSTEP-2
    compute_step(wB, aB0, aB1);                   // step NSTEP-1

    // partials: C/D layout col = lane&15, row = quad*4 + r
    float* wsb = ws + (size_t)blockIdx.y * MM * NN + blockIdx.x * 64
               + wave * 16 + col;
#pragma unroll
    for (int r = 0; r < 4; ++r) {
        int m0 = quad * 4 + r;
        wsb[(size_t)m0 * NN]        = acc0[r];
        wsb[(size_t)(m0 + 16) * NN] = acc1[r];
    }
}

// ---------------- reduce KSPLIT partials, apply scale
template <int KSPLIT>
__global__ __launch_bounds__(256) void finalize_kernel(
    const float* __restrict__ ws,
    const float* __restrict__ scale,
    float*       __restrict__ out)
{
    const int n = blockIdx.x * 256 + threadIdx.x;   // NN = 112*256
    const int m = blockIdx.y;
    float sum = 0.f;
#pragma unroll
    for (int c = 0; c < KSPLIT; ++c)
        sum += ws[(size_t)c * MM * NN + (size_t)m * NN + n];
    out[(size_t)m * NN + n] = sum * scale[n];
}

// ---------------- fallback (ws too small): direct kernel, fused epilogue
__global__ __launch_bounds__(256) void gemm_direct_kernel(
    const float* __restrict__ act,
    const int*   __restrict__ weight,
    const float* __restrict__ scale,
    float*       __restrict__ out)
{
    const int lane = threadIdx.x & 63;
    const int wave = threadIdx.x >> 6;
    const int col  = lane & 15;
    const int quad = lane >> 4;
    const int n0 = blockIdx.x * 64 + wave * 16 + col;

    floatx4 acc0 = {0.f, 0.f, 0.f, 0.f};
    floatx4 acc1 = {0.f, 0.f, 0.f, 0.f};
    const float* ap0 = act + (size_t)col * KK + quad * 8;
    const float* ap1 = ap0 + (size_t)16 * KK;
    const int* wp = weight + (size_t)(quad * 8) * NN + n0;

    for (int s = 0; s < KK / 32; ++s) {
        floatx4 a0lo = *(const floatx4*)(ap0);
        floatx4 a0hi = *(const floatx4*)(ap0 + 4);
        floatx4 a1lo = *(const floatx4*)(ap1);
        floatx4 a1hi = *(const floatx4*)(ap1 + 4);
        half8 a0, a1, b;
#pragma unroll
        for (int j = 0; j < 4; ++j) {
            a0[j] = (_Float16)a0lo[j]; a0[j + 4] = (_Float16)a0hi[j];
            a1[j] = (_Float16)a1lo[j]; a1[j + 4] = (_Float16)a1hi[j];
        }
#pragma unroll
        for (int j = 0; j < 8; ++j)
            b[j] = (_Float16)wp[(size_t)j * NN];
        acc0 = __builtin_amdgcn_mfma_f32_16x16x32_f16(a0, b, acc0, 0, 0, 0);
        acc1 = __builtin_amdgcn_mfma_f32_16x16x32_f16(a1, b, acc1, 0, 0, 0);
        ap0 += 32; ap1 += 32; wp += (size_t)32 * NN;
    }
    float sc = scale[n0];
#pragma unroll
    for (int r = 0; r < 4; ++r) {
        int m0 = quad * 4 + r;
        out[(size_t)m0 * NN + n0]        = acc0[r] * sc;
        out[(size_t)(m0 + 16) * NN + n0] = acc1[r] * sc;
    }
}

extern "C" void kernel_launch(void* const* d_in, const int* in_sizes, int n_in,
                              void* d_out, int out_size, void* d_ws, size_t ws_size,
                              hipStream_t stream)
{
    const float* act    = (const float*)d_in[0];
    const int*   weight = (const int*)d_in[1];
    const float* scale  = (const float*)d_in[2];
    float*       out    = (float*)d_out;

    constexpr int KSPLIT = 4;
    const size_t partials_bytes = (size_t)KSPLIT * MM * NN * sizeof(float); // 14680064
    const size_t act16_off      = partials_bytes;                            // 16B aligned
    const size_t need           = act16_off + (size_t)MM * KK * sizeof(__fp16);

    if (ws_size >= need) {
        float*   ws_part = (float*)d_ws;
        __fp16*  act16   = (__fp16*)((char*)d_ws + act16_off);

        act_cvt_kernel<<<MM * KK / (256 * 4), 256, 0, stream>>>(act, act16);

        dim3 grid(NN / 64, KSPLIT);
        gemm_stream_kernel<KSPLIT><<<grid, 256, 0, stream>>>(act16, weight, ws_part);

        dim3 fgrid(NN / 256, MM);
        finalize_kernel<KSPLIT><<<fgrid, 256, 0, stream>>>(ws_part, scale, out);
    } else {
        gemm_direct_kernel<<<NN / 64, 256, 0, stream>>>(act, weight, scale, out);
    }
}